// Round 25
// baseline (35.945 us; speedup 1.0000x reference)
//
#include <hip/hip_runtime.h>
#include <hip/hip_bf16.h>

#define N_TOT 8192
#define B_HALF 4096
#define D_DIM 256
#define NQUAD 496            // sum floor((64-ti)/4): 4-tile units
#define NSING 96             // sum (64-ti)%4: 1-tile tail units
#define NBLK (NQUAD + NSING) // 592, one dispatch
#define NREP 8               // rowsum replicas (atomic-contention spread)

typedef __attribute__((ext_vector_type(4))) float f32x4;
typedef unsigned long long u64;

// S8SCALE = sqrt(256 * 2*log2(e)). zq = fp8(S8SCALE * z/|z|), so the MFMA acc
// = S8SCALE^2 * sim = 256 * sim * 2*log2(e)  ->  exp(sim/T) = exp2(acc/256).
#define S8SCALE 27.178307f
#define LN2 0.69314718056f

// ---- normalize -> fp8, TRANSPOSED store zt[g][row] (g = 8B K-chunk 0..31) --
__global__ __launch_bounds__(256) void k_norm(const float* __restrict__ p1,
                                              const float* __restrict__ p2,
                                              u64* __restrict__ zt,
                                              float* __restrict__ self,
                                              float* __restrict__ partials,
                                              float* __restrict__ RS,
                                              float* __restrict__ out) {
  __shared__ unsigned sm[2][8][64]; // [half][row-in-block][4B word]
  __shared__ float red[4];
  int tid = threadIdx.x;
  int lane = tid & 63;
  int w = tid >> 6;                 // wave 0..3
  int bid = blockIdx.x;
  int i0 = bid * 8;
  // zero RS: 8 replicas x 8192 floats = 256KB; 512 blocks x 32 x 16B
  if (tid < 32) reinterpret_cast<f32x4*>(RS)[bid * 32 + tid] = (f32x4){0.f, 0.f, 0.f, 0.f};
  if (bid == 0 && tid == 0) out[0] = 0.0f;

  float possum = 0.f;
#pragma unroll
  for (int k = 0; k < 2; ++k) {
    int r = w * 2 + k;              // row-in-block 0..7
    int i = i0 + r;                 // pair index 0..4095
    float4 a = *reinterpret_cast<const float4*>(p1 + (size_t)i * D_DIM + lane * 4);
    float4 b = *reinterpret_cast<const float4*>(p2 + (size_t)i * D_DIM + lane * 4);
    float ssa = a.x * a.x + a.y * a.y + a.z * a.z + a.w * a.w;
    float ssb = b.x * b.x + b.y * b.y + b.z * b.z + b.w * b.w;
    float d = a.x * b.x + a.y * b.y + a.z * b.z + a.w * b.w;
#pragma unroll
    for (int m = 1; m < 64; m <<= 1) {
      ssa += __shfl_xor(ssa, m, 64);
      ssb += __shfl_xor(ssb, m, 64);
      d += __shfl_xor(d, m, 64);
    }
    float na = fmaxf(sqrtf(ssa), 1e-8f);
    float nb = fmaxf(sqrtf(ssb), 1e-8f);
    float ia = S8SCALE / na, ib = S8SCALE / nb;

    int wa = __builtin_amdgcn_cvt_pk_fp8_f32(a.x * ia, a.y * ia, 0, false);
    wa = __builtin_amdgcn_cvt_pk_fp8_f32(a.z * ia, a.w * ia, wa, true);
    int wb = __builtin_amdgcn_cvt_pk_fp8_f32(b.x * ib, b.y * ib, 0, false);
    wb = __builtin_amdgcn_cvt_pk_fp8_f32(b.z * ib, b.w * ib, wb, true);
    sm[0][r][lane] = (unsigned)wa;
    sm[1][r][lane] = (unsigned)wb;

    float va0 = __builtin_amdgcn_cvt_f32_fp8(wa, 0);
    float va1 = __builtin_amdgcn_cvt_f32_fp8(wa, 1);
    float va2 = __builtin_amdgcn_cvt_f32_fp8(wa, 2);
    float va3 = __builtin_amdgcn_cvt_f32_fp8(wa, 3);
    float vb0 = __builtin_amdgcn_cvt_f32_fp8(wb, 0);
    float vb1 = __builtin_amdgcn_cvt_f32_fp8(wb, 1);
    float vb2 = __builtin_amdgcn_cvt_f32_fp8(wb, 2);
    float vb3 = __builtin_amdgcn_cvt_f32_fp8(wb, 3);
    float sqa = va0 * va0 + va1 * va1 + va2 * va2 + va3 * va3;
    float sqb = vb0 * vb0 + vb1 * vb1 + vb2 * vb2 + vb3 * vb3;
#pragma unroll
    for (int m = 1; m < 64; m <<= 1) {
      sqa += __shfl_xor(sqa, m, 64);
      sqb += __shfl_xor(sqb, m, 64);
    }
    if (lane == 0) {
      self[i] = sqa * (1.0f / 256.0f);       // exponent domain (acc/256)
      self[i + B_HALF] = sqb * (1.0f / 256.0f);
      possum += -4.0f * d / (na * nb) * (1.0f / (float)N_TOT);
    }
  }
  if (lane == 0) red[w] = possum;
  __syncthreads();
  if (tid == 0) partials[bid] = red[0] + red[1] + red[2] + red[3];

  // transposed write-out: thread t -> half h, chunk g (0..31), row-quarter qr
  {
    int h = tid >> 7;               // 0..1
    int rem = tid & 127;
    int g = rem >> 2;               // 0..31
    int qr = rem & 3;               // rows qr*2, qr*2+1
    uint4 v;
    v.x = sm[h][qr * 2][g * 2];
    v.y = sm[h][qr * 2][g * 2 + 1];
    v.z = sm[h][qr * 2 + 1][g * 2];
    v.w = sm[h][qr * 2 + 1][g * 2 + 1];
    size_t idx8 = (size_t)g * N_TOT + h * B_HALF + i0 + qr * 2; // 8B units
    *reinterpret_cast<uint4*>((char*)zt + idx8 * 8) = v;
  }
}

// ---- symmetric fused fp8 GEMM + exp sums; 2-deep reg pipeline + deferred ---
// atomics. Per phase t: issue L_{t+1}(16 loads, other buffer) then A_{t-1}
// (2 col-atomics), then wait counted vmcnt for L_t only — every load gets a
// full MFMA+exp phase of latency cover and no atomic ever blocks the pipe.
// Steady-state queue [L_t, A_{t-2}, L_{t+1}, A_{t-1}] -> vmcnt(20).
__global__ __launch_bounds__(256, 1) void k_sim(const u64* __restrict__ zt,
                                                float* __restrict__ RS) {
  const int bid = blockIdx.x;
  int ti = 0, cum = 0, tj0, nt;
  if (bid < NQUAD) {
    while (cum + ((64 - ti) >> 2) <= bid) { cum += (64 - ti) >> 2; ++ti; }
    tj0 = ti + 4 * (bid - cum);
    nt = 4;
  } else {
    const int s = bid - NQUAD;
    while (cum + ((64 - ti) & 3) <= s) { cum += (64 - ti) & 3; ++ti; }
    tj0 = 64 - ((64 - ti) & 3) + (s - cum);
    nt = 1;
  }
  const int nht = 2 * nt;   // 64-col steps (even: 2 or 8)
  const bool diag = (tj0 == ti);
  const int rowbase = ti * 128;
  const int colchunk = tj0 * 128;
  float* __restrict__ rowsum = RS + (size_t)(bid & (NREP - 1)) * N_TOT;

  const int tid = threadIdx.x;
  const int lane = tid & 63;
  const int wid = tid >> 6;
  const int wm = wid >> 1;  // row half
  const int wn = wid & 1;   // col half
  const int hi = lane >> 4; // 0..3
  const int lo = lane & 15;

  const size_t baseA = (size_t)hi * N_TOT + rowbase + wm * 64 + lo;
  const size_t baseB = (size_t)hi * N_TOT + colchunk + wn * 32 + lo;

  // ---- A fragments (64 VGPR), one-time coalesced loads ----
  long af[4][8];
#pragma unroll
  for (int m = 0; m < 4; ++m)
#pragma unroll
    for (int g = 0; g < 8; ++g)
      af[m][g] = (long)zt[(size_t)g * 4 * N_TOT + baseA + m * 16];

  float pr[4][4] = {}; // [m][r] per-row exp partials (rows of ti)
  long bfA[2][8], bfB[2][8];
  float fl0 = 0.f, fl1 = 0.f; // deferred col-sum values (prev phase)
  int colPrev = 0;

  auto loadB = [&](long (&bf)[2][8], int t) {
#pragma unroll
    for (int nb = 0; nb < 2; ++nb)
#pragma unroll
      for (int g = 0; g < 8; ++g)
        bf[nb][g] = (long)zt[(size_t)g * 4 * N_TOT + baseB + t * 64 + nb * 16];
  };

  auto work = [&](const long (&bf)[2][8], int t) {
    f32x4 acc[4][2];
#pragma unroll
    for (int m = 0; m < 4; ++m)
#pragma unroll
      for (int n = 0; n < 2; ++n) acc[m][n] = (f32x4){0.f, 0.f, 0.f, 0.f};
#pragma unroll
    for (int g = 0; g < 8; ++g) {
      acc[0][0] = __builtin_amdgcn_mfma_f32_16x16x32_fp8_fp8(af[0][g], bf[0][g], acc[0][0], 0, 0, 0);
      acc[0][1] = __builtin_amdgcn_mfma_f32_16x16x32_fp8_fp8(af[0][g], bf[1][g], acc[0][1], 0, 0, 0);
      acc[1][0] = __builtin_amdgcn_mfma_f32_16x16x32_fp8_fp8(af[1][g], bf[0][g], acc[1][0], 0, 0, 0);
      acc[1][1] = __builtin_amdgcn_mfma_f32_16x16x32_fp8_fp8(af[1][g], bf[1][g], acc[1][1], 0, 0, 0);
      acc[2][0] = __builtin_amdgcn_mfma_f32_16x16x32_fp8_fp8(af[2][g], bf[0][g], acc[2][0], 0, 0, 0);
      acc[2][1] = __builtin_amdgcn_mfma_f32_16x16x32_fp8_fp8(af[2][g], bf[1][g], acc[2][1], 0, 0, 0);
      acc[3][0] = __builtin_amdgcn_mfma_f32_16x16x32_fp8_fp8(af[3][g], bf[0][g], acc[3][0], 0, 0, 0);
      acc[3][1] = __builtin_amdgcn_mfma_f32_16x16x32_fp8_fp8(af[3][g], bf[1][g], acc[3][1], 0, 0, 0);
    }
    float pc[2] = {0.f, 0.f};
#pragma unroll
    for (int m = 0; m < 4; ++m)
#pragma unroll
      for (int n = 0; n < 2; ++n) {
        float e0 = __builtin_amdgcn_exp2f(acc[m][n][0] * (1.0f / 256.0f));
        float e1 = __builtin_amdgcn_exp2f(acc[m][n][1] * (1.0f / 256.0f));
        float e2 = __builtin_amdgcn_exp2f(acc[m][n][2] * (1.0f / 256.0f));
        float e3 = __builtin_amdgcn_exp2f(acc[m][n][3] * (1.0f / 256.0f));
        pr[m][0] += e0; pr[m][1] += e1; pr[m][2] += e2; pr[m][3] += e3;
        pc[n] += (e0 + e1) + (e2 + e3);
      }
    float v0 = pc[0];
    v0 += __shfl_xor(v0, 16, 64);
    v0 += __shfl_xor(v0, 32, 64);
    float v1 = pc[1];
    v1 += __shfl_xor(v1, 16, 64);
    v1 += __shfl_xor(v1, 32, 64);
    const bool skip = (diag && t < 2);
    fl0 = skip ? 0.f : v0;
    fl1 = skip ? 0.f : v1;
    colPrev = colchunk + t * 64 + wn * 32;
  };

  loadB(bfA, 0); // prologue: L0
#pragma unroll 1
  for (int t = 0; t < nht; t += 2) {
    // ---- phase t (cur = bfA) ----
    loadB(bfB, t + 1); // L_{t+1}
    __builtin_amdgcn_sched_barrier(0);
    if (t > 0 && hi == 0) { // A_{t-1}
      atomicAdd(&rowsum[colPrev + lo], fl0);
      atomicAdd(&rowsum[colPrev + 16 + lo], fl1);
    }
    __builtin_amdgcn_sched_barrier(0);
    if (t == 0) {
      asm volatile("s_waitcnt vmcnt(16)" ::: "memory");
    } else {
      asm volatile("s_waitcnt vmcnt(20)" ::: "memory");
    }
    __builtin_amdgcn_sched_barrier(0);
    work(bfA, t);

    // ---- phase t+1 (cur = bfB) ----
    const bool more = (t + 2 < nht);
    if (more) loadB(bfA, t + 2); // L_{t+2}
    __builtin_amdgcn_sched_barrier(0);
    if (hi == 0) { // A_t
      atomicAdd(&rowsum[colPrev + lo], fl0);
      atomicAdd(&rowsum[colPrev + 16 + lo], fl1);
    }
    __builtin_amdgcn_sched_barrier(0);
    if (more) {
      if (t == 0) {
        asm volatile("s_waitcnt vmcnt(18)" ::: "memory");
      } else {
        asm volatile("s_waitcnt vmcnt(20)" ::: "memory");
      }
    } else {
      if (t == 0) {
        asm volatile("s_waitcnt vmcnt(2)" ::: "memory");
      } else {
        asm volatile("s_waitcnt vmcnt(4)" ::: "memory");
      }
    }
    __builtin_amdgcn_sched_barrier(0);
    work(bfB, t + 1);
  }
  // epilogue: last phase's col-atomics
  if (hi == 0) {
    atomicAdd(&rowsum[colPrev + lo], fl0);
    atomicAdd(&rowsum[colPrev + 16 + lo], fl1);
  }

  // row sums -> rows of ti (reduce over the 16 col-lanes)
#pragma unroll
  for (int m = 0; m < 4; ++m)
#pragma unroll
    for (int r = 0; r < 4; ++r) {
      float s = pr[m][r];
      s += __shfl_xor(s, 1, 64);
      s += __shfl_xor(s, 2, 64);
      s += __shfl_xor(s, 4, 64);
      s += __shfl_xor(s, 8, 64);
      if (lo == 0)
        atomicAdd(&rowsum[rowbase + wm * 64 + m * 16 + hi * 4 + r], s);
    }
}

// ---- final: 32 blocks, out += sum(log(sum_r RS[r] - exp2(self)))/n ---------
__global__ __launch_bounds__(256) void k_lse(const float* __restrict__ RS,
                                             const float* __restrict__ self,
                                             const float* __restrict__ partials,
                                             float* __restrict__ out) {
  int tid = threadIdx.x;
  int i = blockIdx.x * 256 + tid;
  float rs = 0.f;
#pragma unroll
  for (int r = 0; r < NREP; ++r) rs += RS[(size_t)r * N_TOT + i];
  rs -= __builtin_amdgcn_exp2f(self[i]);
  float v = __builtin_amdgcn_logf(rs) * (LN2 / (float)N_TOT); // v_log_f32 = log2
  if (tid < 16) v += partials[blockIdx.x * 16 + tid]; // 512 partials / 32 blocks
#pragma unroll
  for (int m = 1; m < 64; m <<= 1) v += __shfl_xor(v, m, 64);
  __shared__ float red[4];
  if ((tid & 63) == 0) red[tid >> 6] = v;
  __syncthreads();
  if (tid == 0) atomicAdd(out, red[0] + red[1] + red[2] + red[3]);
}

extern "C" void kernel_launch(void* const* d_in, const int* in_sizes, int n_in,
                              void* d_out, int out_size, void* d_ws, size_t ws_size,
                              hipStream_t stream) {
  const float* p1 = (const float*)d_in[0];
  const float* p2 = (const float*)d_in[1];
  float* out = (float*)d_out;
  char* ws = (char*)d_ws;

  u64* zt = (u64*)ws;                                            // 2 MB fp8 (transposed)
  float* self = (float*)(ws + 2097152);                          // 32 KB
  float* RS = self + N_TOT;                                      // 256 KB (8 replicas)
  float* partials = RS + (size_t)NREP * N_TOT;                   // 2 KB

  k_norm<<<N_TOT / 16, 256, 0, stream>>>(p1, p2, zt, self, partials, RS, out);
  k_sim<<<NBLK, 256, 0, stream>>>(zt, RS);
  k_lse<<<N_TOT / 256, 256, 0, stream>>>(RS, self, partials, out);
}

// Round 26
// 34.063 us; speedup vs baseline: 1.0553x; 1.0553x over previous
//
#include <hip/hip_runtime.h>
#include <hip/hip_bf16.h>

#define N_TOT 8192
#define B_HALF 4096
#define D_DIM 256
#define NQUAD 496            // sum floor((64-ti)/4): 4-tile units
#define NSING 96             // sum (64-ti)%4: 1-tile tail units
#define NBLK (NQUAD + NSING) // 592, one dispatch
#define NREP 8               // rowsum replicas (atomic-contention spread)

typedef __attribute__((ext_vector_type(4))) float f32x4;
typedef unsigned long long u64;

// S8SCALE = sqrt(256 * 2*log2(e)). zq = fp8(S8SCALE * z/|z|), so the MFMA acc
// = S8SCALE^2 * sim = 256 * sim * 2*log2(e)  ->  exp(sim/T) = exp2(acc/256).
#define S8SCALE 27.178307f
#define LN2 0.69314718056f

// ---- normalize -> fp8, TRANSPOSED store zt[g][row] (g = 8B K-chunk 0..31) --
__global__ __launch_bounds__(256) void k_norm(const float* __restrict__ p1,
                                              const float* __restrict__ p2,
                                              u64* __restrict__ zt,
                                              float* __restrict__ self,
                                              float* __restrict__ partials,
                                              float* __restrict__ RS,
                                              float* __restrict__ out) {
  __shared__ unsigned sm[2][8][64]; // [half][row-in-block][4B word]
  __shared__ float red[4];
  int tid = threadIdx.x;
  int lane = tid & 63;
  int w = tid >> 6;                 // wave 0..3
  int bid = blockIdx.x;
  int i0 = bid * 8;
  // zero RS: 8 replicas x 8192 floats = 256KB; 512 blocks x 32 x 16B
  if (tid < 32) reinterpret_cast<f32x4*>(RS)[bid * 32 + tid] = (f32x4){0.f, 0.f, 0.f, 0.f};
  if (bid == 0 && tid == 0) out[0] = 0.0f;

  float possum = 0.f;
#pragma unroll
  for (int k = 0; k < 2; ++k) {
    int r = w * 2 + k;              // row-in-block 0..7
    int i = i0 + r;                 // pair index 0..4095
    float4 a = *reinterpret_cast<const float4*>(p1 + (size_t)i * D_DIM + lane * 4);
    float4 b = *reinterpret_cast<const float4*>(p2 + (size_t)i * D_DIM + lane * 4);
    float ssa = a.x * a.x + a.y * a.y + a.z * a.z + a.w * a.w;
    float ssb = b.x * b.x + b.y * b.y + b.z * b.z + b.w * b.w;
    float d = a.x * b.x + a.y * b.y + a.z * b.z + a.w * b.w;
#pragma unroll
    for (int m = 1; m < 64; m <<= 1) {
      ssa += __shfl_xor(ssa, m, 64);
      ssb += __shfl_xor(ssb, m, 64);
      d += __shfl_xor(d, m, 64);
    }
    float na = fmaxf(sqrtf(ssa), 1e-8f);
    float nb = fmaxf(sqrtf(ssb), 1e-8f);
    float ia = S8SCALE / na, ib = S8SCALE / nb;

    int wa = __builtin_amdgcn_cvt_pk_fp8_f32(a.x * ia, a.y * ia, 0, false);
    wa = __builtin_amdgcn_cvt_pk_fp8_f32(a.z * ia, a.w * ia, wa, true);
    int wb = __builtin_amdgcn_cvt_pk_fp8_f32(b.x * ib, b.y * ib, 0, false);
    wb = __builtin_amdgcn_cvt_pk_fp8_f32(b.z * ib, b.w * ib, wb, true);
    sm[0][r][lane] = (unsigned)wa;
    sm[1][r][lane] = (unsigned)wb;

    float va0 = __builtin_amdgcn_cvt_f32_fp8(wa, 0);
    float va1 = __builtin_amdgcn_cvt_f32_fp8(wa, 1);
    float va2 = __builtin_amdgcn_cvt_f32_fp8(wa, 2);
    float va3 = __builtin_amdgcn_cvt_f32_fp8(wa, 3);
    float vb0 = __builtin_amdgcn_cvt_f32_fp8(wb, 0);
    float vb1 = __builtin_amdgcn_cvt_f32_fp8(wb, 1);
    float vb2 = __builtin_amdgcn_cvt_f32_fp8(wb, 2);
    float vb3 = __builtin_amdgcn_cvt_f32_fp8(wb, 3);
    float sqa = va0 * va0 + va1 * va1 + va2 * va2 + va3 * va3;
    float sqb = vb0 * vb0 + vb1 * vb1 + vb2 * vb2 + vb3 * vb3;
#pragma unroll
    for (int m = 1; m < 64; m <<= 1) {
      sqa += __shfl_xor(sqa, m, 64);
      sqb += __shfl_xor(sqb, m, 64);
    }
    if (lane == 0) {
      self[i] = sqa * (1.0f / 256.0f);       // exponent domain (acc/256)
      self[i + B_HALF] = sqb * (1.0f / 256.0f);
      possum += -4.0f * d / (na * nb) * (1.0f / (float)N_TOT);
    }
  }
  if (lane == 0) red[w] = possum;
  __syncthreads();
  if (tid == 0) partials[bid] = red[0] + red[1] + red[2] + red[3];

  // transposed write-out: thread t -> half h, chunk g (0..31), row-quarter qr
  {
    int h = tid >> 7;               // 0..1
    int rem = tid & 127;
    int g = rem >> 2;               // 0..31
    int qr = rem & 3;               // rows qr*2, qr*2+1
    uint4 v;
    v.x = sm[h][qr * 2][g * 2];
    v.y = sm[h][qr * 2][g * 2 + 1];
    v.z = sm[h][qr * 2 + 1][g * 2];
    v.w = sm[h][qr * 2 + 1][g * 2 + 1];
    size_t idx8 = (size_t)g * N_TOT + h * B_HALF + i0 + qr * 2; // 8B units
    *reinterpret_cast<uint4*>((char*)zt + idx8 * 8) = v;
  }
}

// ---- symmetric fused fp8 GEMM + exp sums; A in LDS, 4 blocks/CU ------------
// A band (128 rows x 256 K fp8 = 32KB) staged once into LDS (padded stride 33
// u64 to spread banks); per step each wave re-reads its af frags (4 ds_read_b64
// per g vs 8 MFMAs — off critical path). Register demand ~105 -> VGPR<=128 ->
// 4 waves/SIMD -> 1024 block slots: all 592 blocks ONE generation, 16 waves/CU.
// Deferred col-atomics + counted vmcnt(2) from R24 retained.
__global__ __launch_bounds__(256, 4) void k_sim(const u64* __restrict__ zt,
                                                float* __restrict__ RS) {
  __shared__ u64 A_s[128 * 33]; // 33792 B, padded stride kills bank aliasing

  const int bid = blockIdx.x;
  int ti = 0, cum = 0, tj0, nt;
  if (bid < NQUAD) {
    while (cum + ((64 - ti) >> 2) <= bid) { cum += (64 - ti) >> 2; ++ti; }
    tj0 = ti + 4 * (bid - cum);
    nt = 4;
  } else {
    const int s = bid - NQUAD;
    while (cum + ((64 - ti) & 3) <= s) { cum += (64 - ti) & 3; ++ti; }
    tj0 = 64 - ((64 - ti) & 3) + (s - cum);
    nt = 1;
  }
  const int nht = 2 * nt;   // 64-col steps
  const bool diag = (tj0 == ti);
  const int rowbase = ti * 128;
  const int colchunk = tj0 * 128;
  float* __restrict__ rowsum = RS + (size_t)(bid & (NREP - 1)) * N_TOT;

  const int tid = threadIdx.x;
  const int lane = tid & 63;
  const int wid = tid >> 6;
  const int wm = wid >> 1;  // row half
  const int wn = wid & 1;   // col half
  const int hi = lane >> 4; // 0..3
  const int lo = lane & 15;

  // ---- stage A into LDS: coalesced chunk-major reads, padded writes ----
#pragma unroll
  for (int i = 0; i < 16; ++i) {
    int q = i * 256 + tid;
    int c = q >> 7;        // chunk 0..31
    int row = q & 127;     // 0..127
    A_s[row * 33 + c] = zt[(size_t)c * N_TOT + rowbase + row];
  }
  __syncthreads();

  const size_t baseB = (size_t)hi * N_TOT + colchunk + wn * 32 + lo;
  const int arow = wm * 64 + lo; // this lane's base A row

  float pr[4][4] = {}; // [m][r] per-row exp partials (rows of ti)
  long bf[2][8];       // single-buffered B frags (32 VGPR)
  float fl0 = 0.f, fl1 = 0.f; // deferred col-sum values (prev step)
  int colPrev = 0;

#pragma unroll 1
  for (int t = 0; t < nht; ++t) {
    const int colT = colchunk + t * 64 + wn * 32;
    // (1) issue this step's 16 B-loads
#pragma unroll
    for (int nb = 0; nb < 2; ++nb)
#pragma unroll
      for (int g = 0; g < 8; ++g)
        bf[nb][g] = (long)zt[(size_t)g * 4 * N_TOT + baseB + t * 64 + nb * 16];
    __builtin_amdgcn_sched_barrier(0);
    // (2) previous step's col-atomics — issued AFTER the loads, fly on
    if (t > 0 && hi == 0) {
      atomicAdd(&rowsum[colPrev + lo], fl0);
      atomicAdd(&rowsum[colPrev + 16 + lo], fl1);
    }
    __builtin_amdgcn_sched_barrier(0);
    // (3) wait only this step's loads (2 atomics stay outstanding)
    if (t == 0) {
      asm volatile("s_waitcnt vmcnt(0)" ::: "memory");
    } else {
      asm volatile("s_waitcnt vmcnt(2)" ::: "memory");
    }
    __builtin_amdgcn_sched_barrier(0);

    f32x4 acc[4][2];
#pragma unroll
    for (int m = 0; m < 4; ++m)
#pragma unroll
      for (int n = 0; n < 2; ++n) acc[m][n] = (f32x4){0.f, 0.f, 0.f, 0.f};
#pragma unroll
    for (int g = 0; g < 8; ++g) {
      const int c8 = g * 4 + hi;
      long a0 = (long)A_s[(size_t)(arow)*33 + c8];
      long a1 = (long)A_s[(size_t)(arow + 16) * 33 + c8];
      long a2 = (long)A_s[(size_t)(arow + 32) * 33 + c8];
      long a3 = (long)A_s[(size_t)(arow + 48) * 33 + c8];
      acc[0][0] = __builtin_amdgcn_mfma_f32_16x16x32_fp8_fp8(a0, bf[0][g], acc[0][0], 0, 0, 0);
      acc[0][1] = __builtin_amdgcn_mfma_f32_16x16x32_fp8_fp8(a0, bf[1][g], acc[0][1], 0, 0, 0);
      acc[1][0] = __builtin_amdgcn_mfma_f32_16x16x32_fp8_fp8(a1, bf[0][g], acc[1][0], 0, 0, 0);
      acc[1][1] = __builtin_amdgcn_mfma_f32_16x16x32_fp8_fp8(a1, bf[1][g], acc[1][1], 0, 0, 0);
      acc[2][0] = __builtin_amdgcn_mfma_f32_16x16x32_fp8_fp8(a2, bf[0][g], acc[2][0], 0, 0, 0);
      acc[2][1] = __builtin_amdgcn_mfma_f32_16x16x32_fp8_fp8(a2, bf[1][g], acc[2][1], 0, 0, 0);
      acc[3][0] = __builtin_amdgcn_mfma_f32_16x16x32_fp8_fp8(a3, bf[0][g], acc[3][0], 0, 0, 0);
      acc[3][1] = __builtin_amdgcn_mfma_f32_16x16x32_fp8_fp8(a3, bf[1][g], acc[3][1], 0, 0, 0);
    }

    // retire: exponent = acc/256; row partials + this step's col partials
    float pc[2] = {0.f, 0.f};
#pragma unroll
    for (int m = 0; m < 4; ++m)
#pragma unroll
      for (int n = 0; n < 2; ++n) {
        float e0 = __builtin_amdgcn_exp2f(acc[m][n][0] * (1.0f / 256.0f));
        float e1 = __builtin_amdgcn_exp2f(acc[m][n][1] * (1.0f / 256.0f));
        float e2 = __builtin_amdgcn_exp2f(acc[m][n][2] * (1.0f / 256.0f));
        float e3 = __builtin_amdgcn_exp2f(acc[m][n][3] * (1.0f / 256.0f));
        pr[m][0] += e0; pr[m][1] += e1; pr[m][2] += e2; pr[m][3] += e3;
        pc[n] += (e0 + e1) + (e2 + e3);
      }
    // reduce col partials now; emit atomics next iteration
    float v0 = pc[0];
    v0 += __shfl_xor(v0, 16, 64);
    v0 += __shfl_xor(v0, 32, 64);
    float v1 = pc[1];
    v1 += __shfl_xor(v1, 16, 64);
    v1 += __shfl_xor(v1, 32, 64);
    const bool skip = (diag && t < 2);
    fl0 = skip ? 0.f : v0;
    fl1 = skip ? 0.f : v1;
    colPrev = colT;
  }
  // epilogue: last step's col-atomics
  if (hi == 0) {
    atomicAdd(&rowsum[colPrev + lo], fl0);
    atomicAdd(&rowsum[colPrev + 16 + lo], fl1);
  }

  // row sums -> rows of ti (reduce over the 16 col-lanes)
#pragma unroll
  for (int m = 0; m < 4; ++m)
#pragma unroll
    for (int r = 0; r < 4; ++r) {
      float s = pr[m][r];
      s += __shfl_xor(s, 1, 64);
      s += __shfl_xor(s, 2, 64);
      s += __shfl_xor(s, 4, 64);
      s += __shfl_xor(s, 8, 64);
      if (lo == 0)
        atomicAdd(&rowsum[rowbase + wm * 64 + m * 16 + hi * 4 + r], s);
    }
}

// ---- final: 32 blocks, out += sum(log(sum_r RS[r] - exp2(self)))/n ---------
__global__ __launch_bounds__(256) void k_lse(const float* __restrict__ RS,
                                             const float* __restrict__ self,
                                             const float* __restrict__ partials,
                                             float* __restrict__ out) {
  int tid = threadIdx.x;
  int i = blockIdx.x * 256 + tid;
  float rs = 0.f;
#pragma unroll
  for (int r = 0; r < NREP; ++r) rs += RS[(size_t)r * N_TOT + i];
  rs -= __builtin_amdgcn_exp2f(self[i]);
  float v = __builtin_amdgcn_logf(rs) * (LN2 / (float)N_TOT); // v_log_f32 = log2
  if (tid < 16) v += partials[blockIdx.x * 16 + tid]; // 512 partials / 32 blocks
#pragma unroll
  for (int m = 1; m < 64; m <<= 1) v += __shfl_xor(v, m, 64);
  __shared__ float red[4];
  if ((tid & 63) == 0) red[tid >> 6] = v;
  __syncthreads();
  if (tid == 0) atomicAdd(out, red[0] + red[1] + red[2] + red[3]);
}

extern "C" void kernel_launch(void* const* d_in, const int* in_sizes, int n_in,
                              void* d_out, int out_size, void* d_ws, size_t ws_size,
                              hipStream_t stream) {
  const float* p1 = (const float*)d_in[0];
  const float* p2 = (const float*)d_in[1];
  float* out = (float*)d_out;
  char* ws = (char*)d_ws;

  u64* zt = (u64*)ws;                                            // 2 MB fp8 (transposed)
  float* self = (float*)(ws + 2097152);                          // 32 KB
  float* RS = self + N_TOT;                                      // 256 KB (8 replicas)
  float* partials = RS + (size_t)NREP * N_TOT;                   // 2 KB

  k_norm<<<N_TOT / 16, 256, 0, stream>>>(p1, p2, zt, self, partials, RS, out);
  k_sim<<<NBLK, 256, 0, stream>>>(zt, RS);
  k_lse<<<N_TOT / 256, 256, 0, stream>>>(RS, self, partials, out);
}

// Round 27
// 32.723 us; speedup vs baseline: 1.0985x; 1.0409x over previous
//
#include <hip/hip_runtime.h>
#include <hip/hip_bf16.h>

#define N_TOT 8192
#define B_HALF 4096
#define D_DIM 256
#define NQUAD 496            // sum floor((64-ti)/4): 4-tile units
#define NSING 96             // sum (64-ti)%4: 1-tile tail units
#define NBLK (NQUAD + NSING) // 592, one dispatch
#define NREP 8               // rowsum replicas (atomic-contention spread)

typedef __attribute__((ext_vector_type(4))) float f32x4;
typedef unsigned long long u64;

// S8SCALE = sqrt(256 * 2*log2(e)). zq = fp8(S8SCALE * z/|z|), so the MFMA acc
// = S8SCALE^2 * sim = 256 * sim * 2*log2(e)  ->  exp(sim/T) = exp2(acc/256).
#define S8SCALE 27.178307f
#define LN2 0.69314718056f

// ---- normalize -> fp8, TRANSPOSED store zt[g][row] (g = 8B K-chunk 0..31) --
__global__ __launch_bounds__(256) void k_norm(const float* __restrict__ p1,
                                              const float* __restrict__ p2,
                                              u64* __restrict__ zt,
                                              float* __restrict__ self,
                                              float* __restrict__ partials,
                                              float* __restrict__ RS,
                                              float* __restrict__ out) {
  __shared__ unsigned sm[2][8][64]; // [half][row-in-block][4B word]
  __shared__ float red[4];
  int tid = threadIdx.x;
  int lane = tid & 63;
  int w = tid >> 6;                 // wave 0..3
  int bid = blockIdx.x;
  int i0 = bid * 8;
  // zero RS: 8 replicas x 8192 floats = 256KB; 512 blocks x 32 x 16B
  if (tid < 32) reinterpret_cast<f32x4*>(RS)[bid * 32 + tid] = (f32x4){0.f, 0.f, 0.f, 0.f};
  if (bid == 0 && tid == 0) out[0] = 0.0f;

  float possum = 0.f;
#pragma unroll
  for (int k = 0; k < 2; ++k) {
    int r = w * 2 + k;              // row-in-block 0..7
    int i = i0 + r;                 // pair index 0..4095
    float4 a = *reinterpret_cast<const float4*>(p1 + (size_t)i * D_DIM + lane * 4);
    float4 b = *reinterpret_cast<const float4*>(p2 + (size_t)i * D_DIM + lane * 4);
    float ssa = a.x * a.x + a.y * a.y + a.z * a.z + a.w * a.w;
    float ssb = b.x * b.x + b.y * b.y + b.z * b.z + b.w * b.w;
    float d = a.x * b.x + a.y * b.y + a.z * b.z + a.w * b.w;
#pragma unroll
    for (int m = 1; m < 64; m <<= 1) {
      ssa += __shfl_xor(ssa, m, 64);
      ssb += __shfl_xor(ssb, m, 64);
      d += __shfl_xor(d, m, 64);
    }
    float na = fmaxf(sqrtf(ssa), 1e-8f);
    float nb = fmaxf(sqrtf(ssb), 1e-8f);
    float ia = S8SCALE / na, ib = S8SCALE / nb;

    int wa = __builtin_amdgcn_cvt_pk_fp8_f32(a.x * ia, a.y * ia, 0, false);
    wa = __builtin_amdgcn_cvt_pk_fp8_f32(a.z * ia, a.w * ia, wa, true);
    int wb = __builtin_amdgcn_cvt_pk_fp8_f32(b.x * ib, b.y * ib, 0, false);
    wb = __builtin_amdgcn_cvt_pk_fp8_f32(b.z * ib, b.w * ib, wb, true);
    sm[0][r][lane] = (unsigned)wa;
    sm[1][r][lane] = (unsigned)wb;

    float va0 = __builtin_amdgcn_cvt_f32_fp8(wa, 0);
    float va1 = __builtin_amdgcn_cvt_f32_fp8(wa, 1);
    float va2 = __builtin_amdgcn_cvt_f32_fp8(wa, 2);
    float va3 = __builtin_amdgcn_cvt_f32_fp8(wa, 3);
    float vb0 = __builtin_amdgcn_cvt_f32_fp8(wb, 0);
    float vb1 = __builtin_amdgcn_cvt_f32_fp8(wb, 1);
    float vb2 = __builtin_amdgcn_cvt_f32_fp8(wb, 2);
    float vb3 = __builtin_amdgcn_cvt_f32_fp8(wb, 3);
    float sqa = va0 * va0 + va1 * va1 + va2 * va2 + va3 * va3;
    float sqb = vb0 * vb0 + vb1 * vb1 + vb2 * vb2 + vb3 * vb3;
#pragma unroll
    for (int m = 1; m < 64; m <<= 1) {
      sqa += __shfl_xor(sqa, m, 64);
      sqb += __shfl_xor(sqb, m, 64);
    }
    if (lane == 0) {
      self[i] = sqa * (1.0f / 256.0f);       // exponent domain (acc/256)
      self[i + B_HALF] = sqb * (1.0f / 256.0f);
      possum += -4.0f * d / (na * nb) * (1.0f / (float)N_TOT);
    }
  }
  if (lane == 0) red[w] = possum;
  __syncthreads();
  if (tid == 0) partials[bid] = red[0] + red[1] + red[2] + red[3];

  // transposed write-out: thread t -> half h, chunk g (0..31), row-quarter qr
  {
    int h = tid >> 7;               // 0..1
    int rem = tid & 127;
    int g = rem >> 2;               // 0..31
    int qr = rem & 3;               // rows qr*2, qr*2+1
    uint4 v;
    v.x = sm[h][qr * 2][g * 2];
    v.y = sm[h][qr * 2][g * 2 + 1];
    v.z = sm[h][qr * 2 + 1][g * 2];
    v.w = sm[h][qr * 2 + 1][g * 2 + 1];
    size_t idx8 = (size_t)g * N_TOT + h * B_HALF + i0 + qr * 2; // 8B units
    *reinterpret_cast<uint4*>((char*)zt + idx8 * 8) = v;
  }
}

// ---- symmetric fused fp8 GEMM + exp sums; LDS-accumulated partials ---------
// All col/row partial sums accumulate in LDS (slot owner = unique wave, plain
// LDS RMW, no per-step barriers) and flush ONCE per block: global atomic count
// drops ~770K -> ~350K and leaves the per-step critical path entirely.
// A band in LDS keeps VGPR ~100 -> 4 blocks/CU.
__global__ __launch_bounds__(256, 4) void k_sim(const u64* __restrict__ zt,
                                                float* __restrict__ RS) {
  __shared__ u64 A_s[128 * 33];       // 33 KB, padded stride
  __shared__ float colsum[2][512];    // [wm][block-local col] (owner-unique)
  __shared__ float rowpart[2][128];   // [wn][block-local row] (owner-unique)

  const int bid = blockIdx.x;
  int ti = 0, cum = 0, tj0, nt;
  if (bid < NQUAD) {
    while (cum + ((64 - ti) >> 2) <= bid) { cum += (64 - ti) >> 2; ++ti; }
    tj0 = ti + 4 * (bid - cum);
    nt = 4;
  } else {
    const int s = bid - NQUAD;
    while (cum + ((64 - ti) & 3) <= s) { cum += (64 - ti) & 3; ++ti; }
    tj0 = 64 - ((64 - ti) & 3) + (s - cum);
    nt = 1;
  }
  const int nht = 2 * nt;   // 64-col steps
  const bool diag = (tj0 == ti);
  const int rowbase = ti * 128;
  const int colchunk = tj0 * 128;
  float* __restrict__ rowsum = RS + (size_t)(bid & (NREP - 1)) * N_TOT;

  const int tid = threadIdx.x;
  const int lane = tid & 63;
  const int wid = tid >> 6;
  const int wm = wid >> 1;  // row half
  const int wn = wid & 1;   // col half
  const int hi = lane >> 4; // 0..3
  const int lo = lane & 15;

  // ---- stage A into LDS (coalesced chunk-major reads) + zero accumulators --
#pragma unroll
  for (int i = 0; i < 16; ++i) {
    int q = i * 256 + tid;
    int c = q >> 7;        // chunk 0..31
    int row = q & 127;     // 0..127
    A_s[row * 33 + c] = zt[(size_t)c * N_TOT + rowbase + row];
  }
#pragma unroll
  for (int i = 0; i < 4; ++i) colsum[0][i * 256 + tid] = 0.f; // covers [2][512]
  if (tid < 256) { rowpart[0][tid & 127] = 0.f; rowpart[1][tid & 127] = 0.f; }
  __syncthreads();

  const size_t baseB = (size_t)hi * N_TOT + colchunk + wn * 32 + lo;
  const int arow = wm * 64 + lo;

  float pr[4][4] = {}; // [m][r] per-row exp partials (rows of ti)
  long bf[2][8];       // single-buffered B frags (32 VGPR)

#pragma unroll 1
  for (int t = 0; t < nht; ++t) {
    // issue this step's 16 B-loads, wait, compute
#pragma unroll
    for (int nb = 0; nb < 2; ++nb)
#pragma unroll
      for (int g = 0; g < 8; ++g)
        bf[nb][g] = (long)zt[(size_t)g * 4 * N_TOT + baseB + t * 64 + nb * 16];
    asm volatile("s_waitcnt vmcnt(0)" ::: "memory");
    __builtin_amdgcn_sched_barrier(0);

    f32x4 acc[4][2];
#pragma unroll
    for (int m = 0; m < 4; ++m)
#pragma unroll
      for (int n = 0; n < 2; ++n) acc[m][n] = (f32x4){0.f, 0.f, 0.f, 0.f};
#pragma unroll
    for (int g = 0; g < 8; ++g) {
      const int c8 = g * 4 + hi;
      long a0 = (long)A_s[(size_t)(arow)*33 + c8];
      long a1 = (long)A_s[(size_t)(arow + 16) * 33 + c8];
      long a2 = (long)A_s[(size_t)(arow + 32) * 33 + c8];
      long a3 = (long)A_s[(size_t)(arow + 48) * 33 + c8];
      acc[0][0] = __builtin_amdgcn_mfma_f32_16x16x32_fp8_fp8(a0, bf[0][g], acc[0][0], 0, 0, 0);
      acc[0][1] = __builtin_amdgcn_mfma_f32_16x16x32_fp8_fp8(a0, bf[1][g], acc[0][1], 0, 0, 0);
      acc[1][0] = __builtin_amdgcn_mfma_f32_16x16x32_fp8_fp8(a1, bf[0][g], acc[1][0], 0, 0, 0);
      acc[1][1] = __builtin_amdgcn_mfma_f32_16x16x32_fp8_fp8(a1, bf[1][g], acc[1][1], 0, 0, 0);
      acc[2][0] = __builtin_amdgcn_mfma_f32_16x16x32_fp8_fp8(a2, bf[0][g], acc[2][0], 0, 0, 0);
      acc[2][1] = __builtin_amdgcn_mfma_f32_16x16x32_fp8_fp8(a2, bf[1][g], acc[2][1], 0, 0, 0);
      acc[3][0] = __builtin_amdgcn_mfma_f32_16x16x32_fp8_fp8(a3, bf[0][g], acc[3][0], 0, 0, 0);
      acc[3][1] = __builtin_amdgcn_mfma_f32_16x16x32_fp8_fp8(a3, bf[1][g], acc[3][1], 0, 0, 0);
    }

    // retire: exponent = acc/256; row partials + col partials -> LDS
    float pc[2] = {0.f, 0.f};
#pragma unroll
    for (int m = 0; m < 4; ++m)
#pragma unroll
      for (int n = 0; n < 2; ++n) {
        float e0 = __builtin_amdgcn_exp2f(acc[m][n][0] * (1.0f / 256.0f));
        float e1 = __builtin_amdgcn_exp2f(acc[m][n][1] * (1.0f / 256.0f));
        float e2 = __builtin_amdgcn_exp2f(acc[m][n][2] * (1.0f / 256.0f));
        float e3 = __builtin_amdgcn_exp2f(acc[m][n][3] * (1.0f / 256.0f));
        pr[m][0] += e0; pr[m][1] += e1; pr[m][2] += e2; pr[m][3] += e3;
        pc[n] += (e0 + e1) + (e2 + e3);
      }
    if (!(diag && t < 2)) {
      float v0 = pc[0];
      v0 += __shfl_xor(v0, 16, 64);
      v0 += __shfl_xor(v0, 32, 64);
      float v1 = pc[1];
      v1 += __shfl_xor(v1, 16, 64);
      v1 += __shfl_xor(v1, 32, 64);
      if (hi == 0) { // slot [wm][...] owned by this wave (wn splits col range)
        const int c = t * 64 + wn * 32 + lo;
        colsum[wm][c] += v0;
        colsum[wm][c + 16] += v1;
      }
    }
  }

  // row partials -> LDS (slot [wn][...] owned by this wave)
#pragma unroll
  for (int m = 0; m < 4; ++m)
#pragma unroll
    for (int r = 0; r < 4; ++r) {
      float s = pr[m][r];
      s += __shfl_xor(s, 1, 64);
      s += __shfl_xor(s, 2, 64);
      s += __shfl_xor(s, 4, 64);
      s += __shfl_xor(s, 8, 64);
      if (lo == 0)
        rowpart[wn][wm * 64 + m * 16 + hi * 4 + r] = s;
    }
  __syncthreads();

  // ---- single batched flush: ~640 global atomics per block (fire & forget)
  const int ncols = nht * 64;
  const int c0 = diag ? 128 : 0; // diag tile's cols were skipped (zero)
  for (int c = c0 + tid; c < ncols; c += 256)
    atomicAdd(&rowsum[colchunk + c], colsum[0][c] + colsum[1][c]);
  if (tid < 128)
    atomicAdd(&rowsum[rowbase + tid], rowpart[0][tid] + rowpart[1][tid]);
}

// ---- final: 32 blocks, out += sum(log(sum_r RS[r] - exp2(self)))/n ---------
__global__ __launch_bounds__(256) void k_lse(const float* __restrict__ RS,
                                             const float* __restrict__ self,
                                             const float* __restrict__ partials,
                                             float* __restrict__ out) {
  int tid = threadIdx.x;
  int i = blockIdx.x * 256 + tid;
  float rs = 0.f;
#pragma unroll
  for (int r = 0; r < NREP; ++r) rs += RS[(size_t)r * N_TOT + i];
  rs -= __builtin_amdgcn_exp2f(self[i]);
  float v = __builtin_amdgcn_logf(rs) * (LN2 / (float)N_TOT); // v_log_f32 = log2
  if (tid < 16) v += partials[blockIdx.x * 16 + tid]; // 512 partials / 32 blocks
#pragma unroll
  for (int m = 1; m < 64; m <<= 1) v += __shfl_xor(v, m, 64);
  __shared__ float red[4];
  if ((tid & 63) == 0) red[tid >> 6] = v;
  __syncthreads();
  if (tid == 0) atomicAdd(out, red[0] + red[1] + red[2] + red[3]);
}

extern "C" void kernel_launch(void* const* d_in, const int* in_sizes, int n_in,
                              void* d_out, int out_size, void* d_ws, size_t ws_size,
                              hipStream_t stream) {
  const float* p1 = (const float*)d_in[0];
  const float* p2 = (const float*)d_in[1];
  float* out = (float*)d_out;
  char* ws = (char*)d_ws;

  u64* zt = (u64*)ws;                                            // 2 MB fp8 (transposed)
  float* self = (float*)(ws + 2097152);                          // 32 KB
  float* RS = self + N_TOT;                                      // 256 KB (8 replicas)
  float* partials = RS + (size_t)NREP * N_TOT;                   // 2 KB

  k_norm<<<N_TOT / 16, 256, 0, stream>>>(p1, p2, zt, self, partials, RS, out);
  k_sim<<<NBLK, 256, 0, stream>>>(zt, RS);
  k_lse<<<N_TOT / 256, 256, 0, stream>>>(RS, self, partials, out);
}